// Round 1
// baseline (1415.961 us; speedup 1.0000x reference)
//
#include <hip/hip_runtime.h>
#include <hip/hip_bf16.h>
#include <math.h>

#define NHh 16
#define DHh 64
#define DMh 1024
#define QLENh 1024
#define MLENh 1024
#define BSZh 2
#define KLENh 2048
#define HIDh 1024
#define SCALEh 0.125f

// ---------------------------------------------------------------------------
// Tiled fp32 GEMM: C[m][n] = sum_k A[m][k] * B[n][k]   (A,B row-major, K=1024)
// BM=BN=128, BK=16, 256 threads, 8x8 per thread.
// MODE 0: A row gathered from mems(A0)/w(A1); epilogue scatters q/k/v with biases.
// MODE 1: plain A; epilogue scatters to RK[n][j][d].
// MODE 2: plain A; epilogue writes row-major out.
// ---------------------------------------------------------------------------
template<int MODE>
__global__ __launch_bounds__(256)
void gemm_k(const float* __restrict__ A0, const float* __restrict__ A1,
            const float* __restrict__ Bmat,
            float* __restrict__ O0, float* __restrict__ O1,
            float* __restrict__ O2, float* __restrict__ O3,
            const float* __restrict__ rwb, const float* __restrict__ rrb)
{
    __shared__ float As[16][128];
    __shared__ float Bs[16][128];

    const int tid = threadIdx.x;
    const int tx = tid & 15, ty = tid >> 4;
    const int n0 = blockIdx.x * 128;
    const int m0 = blockIdx.y * 128;

    float acc[8][8];
#pragma unroll
    for (int i = 0; i < 8; ++i)
#pragma unroll
        for (int j = 0; j < 8; ++j) acc[i][j] = 0.f;

    for (int k0 = 0; k0 < 1024; k0 += 16) {
        __syncthreads();
#pragma unroll
        for (int cc = 0; cc < 2; ++cc) {
            int c = tid + cc * 256;          // 0..511
            int row = c >> 2;                // 0..127
            int kq = (c & 3) * 4;            // 0,4,8,12
            int m = m0 + row;
            const float* ap;
            if (MODE == 0) ap = (m < 2048) ? (A0 + (size_t)m * DMh)
                                           : (A1 + (size_t)(m - 2048) * DMh);
            else           ap = A0 + (size_t)m * DMh;
            float4 va = *reinterpret_cast<const float4*>(ap + k0 + kq);
            As[kq + 0][row] = va.x; As[kq + 1][row] = va.y;
            As[kq + 2][row] = va.z; As[kq + 3][row] = va.w;

            float4 vb = *reinterpret_cast<const float4*>(
                Bmat + (size_t)(n0 + row) * DMh + k0 + kq);
            Bs[kq + 0][row] = vb.x; Bs[kq + 1][row] = vb.y;
            Bs[kq + 2][row] = vb.z; Bs[kq + 3][row] = vb.w;
        }
        __syncthreads();
#pragma unroll
        for (int kk = 0; kk < 16; ++kk) {
            float4 a0 = *reinterpret_cast<const float4*>(&As[kk][ty * 8]);
            float4 a1 = *reinterpret_cast<const float4*>(&As[kk][ty * 8 + 4]);
            float4 b0 = *reinterpret_cast<const float4*>(&Bs[kk][tx * 8]);
            float4 b1 = *reinterpret_cast<const float4*>(&Bs[kk][tx * 8 + 4]);
            float a[8] = {a0.x, a0.y, a0.z, a0.w, a1.x, a1.y, a1.z, a1.w};
            float b[8] = {b0.x, b0.y, b0.z, b0.w, b1.x, b1.y, b1.z, b1.w};
#pragma unroll
            for (int u = 0; u < 8; ++u)
#pragma unroll
                for (int v = 0; v < 8; ++v) acc[u][v] += a[u] * b[v];
        }
    }

    if (MODE == 2) {
#pragma unroll
        for (int u = 0; u < 8; ++u) {
            int m = m0 + ty * 8 + u;
#pragma unroll
            for (int v = 0; v < 8; ++v) {
                int c = n0 + tx * 8 + v;
                O0[(size_t)m * 1024 + c] = acc[u][v];
            }
        }
    } else if (MODE == 1) {
        // out[j=m][c] -> RK[(c>>6)][j][c&63]
#pragma unroll
        for (int u = 0; u < 8; ++u) {
            int m = m0 + ty * 8 + u;
#pragma unroll
            for (int v = 0; v < 8; ++v) {
                int c = n0 + tx * 8 + v;
                int nn = c >> 6, d = c & 63;
                O0[(((size_t)nn * KLENh + m) << 6) + d] = acc[u][v];
            }
        }
    } else {
        const int sec = n0 >> 10;   // uniform per block (128 | 1024)
#pragma unroll
        for (int u = 0; u < 8; ++u) {
            int m = m0 + ty * 8 + u;
            int bb = m & 1, t = m >> 1;
#pragma unroll
            for (int v = 0; v < 8; ++v) {
                int c = n0 + tx * 8 + v;
                float val = acc[u][v];
                if (sec == 0) {
                    if (t >= MLENh) {
                        int i = t - MLENh;
                        int cc = c;
                        int nn = cc >> 6, d = cc & 63;
                        size_t idx = (((size_t)(bb * NHh + nn) * QLENh + i) << 6) + d;
                        O0[idx] = val + rwb[cc];   // Qw
                        O1[idx] = val + rrb[cc];   // Qr
                    }
                } else if (sec == 1) {
                    int cc = c - 1024;
                    int nn = cc >> 6, d = cc & 63;
                    O2[(((size_t)(bb * NHh + nn) * KLENh + t) << 6) + d] = val;  // K
                } else {
                    int cc = c - 2048;
                    int nn = cc >> 6, d = cc & 63;
                    O3[(((size_t)(bb * NHh + nn) * KLENh + t) << 6) + d] = val;  // V
                }
            }
        }
    }
}

// ---------------------------------------------------------------------------
// Scores: s[i][j] = (Qw_i·K_j + Qr_i·RK[1023-i+j]) * scale, write raw s to the
// prob area of d_out, and per-row online (max, sumexp) -> stats (m, 1/l).
// Block: 32 rows x (loop of 32 tiles of 64 cols), 256 threads, 2x4 per thread.
// ---------------------------------------------------------------------------
__global__ __launch_bounds__(256)
void score_k(const float* __restrict__ Qw, const float* __restrict__ Qr,
             const float* __restrict__ Kt, const float* __restrict__ RK,
             float* __restrict__ prob, float* __restrict__ stats)
{
    __shared__ float Qws[64][32];   // [d][i]
    __shared__ float Qrs[64][32];
    __shared__ float Ks [64][64];   // [d][j]
    __shared__ float RKs[64][96];   // [d][r_local]
    __shared__ float redm[32][17];
    __shared__ float redl[32][17];

    const int tid = threadIdx.x;
    const int tx = tid & 15, ty = tid >> 4;
    const int i0 = blockIdx.x * 32;
    const int n  = blockIdx.y, b = blockIdx.z;
    const int bn = b * NHh + n;

    const float* Qwb = Qw + (size_t)bn * QLENh * 64;
    const float* Qrb = Qr + (size_t)bn * QLENh * 64;
    const float* Ktb = Kt + (size_t)bn * KLENh * 64;
    const float* RKb = RK + (size_t)n  * KLENh * 64;
    float* probb = prob + (size_t)bn * QLENh * KLENh;

    // stage Q tiles (transposed), once
#pragma unroll
    for (int cc = 0; cc < 2; ++cc) {
        int c = tid + cc * 256;          // 0..511
        int i = c & 31;
        int dq = (c >> 5) << 2;          // 0..60
        float4 v = *reinterpret_cast<const float4*>(Qwb + (size_t)(i0 + i) * 64 + dq);
        Qws[dq + 0][i] = v.x; Qws[dq + 1][i] = v.y;
        Qws[dq + 2][i] = v.z; Qws[dq + 3][i] = v.w;
        float4 w = *reinterpret_cast<const float4*>(Qrb + (size_t)(i0 + i) * 64 + dq);
        Qrs[dq + 0][i] = w.x; Qrs[dq + 1][i] = w.y;
        Qrs[dq + 2][i] = w.z; Qrs[dq + 3][i] = w.w;
    }

    const int il0 = ty * 2;
    const int jl0 = tx * 4;
    float mrun[2] = {-INFINITY, -INFINITY};
    float lrun[2] = {0.f, 0.f};

    for (int jt = 0; jt < 32; ++jt) {
        const int j0 = jt * 64;
        __syncthreads();
        // stage K tile: thread owns row j = tid&63
        {
            int j = tid & 63;
            int dq0 = (tid >> 6) * 4;
#pragma unroll
            for (int kx = 0; kx < 4; ++kx) {
                int dq = dq0 + kx * 16;
                float4 v = *reinterpret_cast<const float4*>(
                    Ktb + (size_t)(j0 + j) * 64 + dq);
                Ks[dq + 0][j] = v.x; Ks[dq + 1][j] = v.y;
                Ks[dq + 2][j] = v.z; Ks[dq + 3][j] = v.w;
            }
        }
        // stage RK window: rows base..base+95 (clamped; clamped rows only feed
        // masked score elements)
        {
            int base = 992 - i0 + j0;
#pragma unroll
            for (int kx = 0; kx < 6; ++kx) {
                int c = tid + kx * 256;        // 0..1535
                int rl = c % 96;
                int dq = (c / 96) * 4;
                int rg = base + rl;
                rg = rg < 0 ? 0 : (rg > 2047 ? 2047 : rg);
                float4 v = *reinterpret_cast<const float4*>(
                    RKb + (size_t)rg * 64 + dq);
                RKs[dq + 0][rl] = v.x; RKs[dq + 1][rl] = v.y;
                RKs[dq + 2][rl] = v.z; RKs[dq + 3][rl] = v.w;
            }
        }
        __syncthreads();

        float acc[2][4] = {{0.f,0.f,0.f,0.f},{0.f,0.f,0.f,0.f}};
        const int cb = 30 - il0 + jl0;   // rk_local(t,u) = cb + 1 + u - t
#pragma unroll 16
        for (int d = 0; d < 64; ++d) {
            float qw0 = Qws[d][il0], qw1 = Qws[d][il0 + 1];
            float qr0 = Qrs[d][il0], qr1 = Qrs[d][il0 + 1];
            float k0v = Ks[d][jl0 + 0], k1v = Ks[d][jl0 + 1];
            float k2v = Ks[d][jl0 + 2], k3v = Ks[d][jl0 + 3];
            float r0 = RKs[d][cb + 0], r1 = RKs[d][cb + 1], r2 = RKs[d][cb + 2];
            float r3 = RKs[d][cb + 3], r4 = RKs[d][cb + 4];
            acc[0][0] += qw0 * k0v + qr0 * r1;
            acc[0][1] += qw0 * k1v + qr0 * r2;
            acc[0][2] += qw0 * k2v + qr0 * r3;
            acc[0][3] += qw0 * k3v + qr0 * r4;
            acc[1][0] += qw1 * k0v + qr1 * r0;
            acc[1][1] += qw1 * k1v + qr1 * r1;
            acc[1][2] += qw1 * k2v + qr1 * r2;
            acc[1][3] += qw1 * k3v + qr1 * r3;
        }

#pragma unroll
        for (int t = 0; t < 2; ++t) {
            int i = i0 + il0 + t;
            float s[4];
            float tm = -INFINITY;
#pragma unroll
            for (int u = 0; u < 4; ++u) {
                s[u] = acc[t][u] * SCALEh;
                int j = j0 + jl0 + u;
                if (j <= i + MLENh) tm = fmaxf(tm, s[u]);
            }
            float4 sv = {s[0], s[1], s[2], s[3]};
            *reinterpret_cast<float4*>(probb + (size_t)i * KLENh + j0 + jl0) = sv;
            if (tm > -INFINITY) {
                float mnew = fmaxf(mrun[t], tm);
                float sc = __expf(mrun[t] - mnew);   // exp(-inf)=0 first time
                float add = 0.f;
#pragma unroll
                for (int u = 0; u < 4; ++u) {
                    int j = j0 + jl0 + u;
                    if (j <= i + MLENh) add += __expf(s[u] - mnew);
                }
                lrun[t] = lrun[t] * sc + add;
                mrun[t] = mnew;
            }
        }
    }

    __syncthreads();
    redm[il0 + 0][tx] = mrun[0]; redl[il0 + 0][tx] = lrun[0];
    redm[il0 + 1][tx] = mrun[1]; redl[il0 + 1][tx] = lrun[1];
    __syncthreads();
    if (tid < 32) {
        float m = -INFINITY;
        for (int x = 0; x < 16; ++x) m = fmaxf(m, redm[tid][x]);
        float l = 0.f;
        for (int x = 0; x < 16; ++x) l += redl[tid][x] * __expf(redm[tid][x] - m);
        stats[((size_t)bn * QLENh + i0 + tid) * 2 + 0] = m;
        stats[((size_t)bn * QLENh + i0 + tid) * 2 + 1] = 1.0f / l;
    }
}

// ---------------------------------------------------------------------------
// prob = softmax(s) written in place (masked -> exactly 0), attn_vec = P @ V.
// Block: 32 rows x DH, loop 32 tiles of 64 kv-positions. 256 threads.
// ---------------------------------------------------------------------------
__global__ __launch_bounds__(256)
void attnv_k(const float* __restrict__ Vt, const float* __restrict__ stats,
             float* __restrict__ prob, float* __restrict__ av)
{
    __shared__ float Ps[32][65];
    __shared__ float Vs[64][65];

    const int tid = threadIdx.x;
    const int i0 = blockIdx.x * 32;
    const int n  = blockIdx.y, b = blockIdx.z;
    const int bn = b * NHh + n;

    float* probb   = prob + (size_t)bn * QLENh * KLENh;
    const float* Vb = Vt + (size_t)bn * KLENh * 64;

    const int srow = tid >> 3;            // S-processing row
    const int sc8  = (tid & 7) * 8;       // S-processing col base
    const float sm  = stats[((size_t)bn * QLENh + i0 + srow) * 2 + 0];
    const float srl = stats[((size_t)bn * QLENh + i0 + srow) * 2 + 1];
    const int ilim = i0 + srow + MLENh;   // j <= ilim unmasked

    const int d0 = (tid & 31) * 2;        // output cols d0, d0+1
    const int rg = tid >> 5;              // output rows rg*4..+3
    float acc[4][2];
#pragma unroll
    for (int u = 0; u < 4; ++u) { acc[u][0] = 0.f; acc[u][1] = 0.f; }

    for (int jt = 0; jt < 32; ++jt) {
        const int j0 = jt * 64;
        __syncthreads();
        // S tile -> P (in place) + LDS
#pragma unroll
        for (int h = 0; h < 2; ++h) {
            int jc = sc8 + h * 4;
            size_t gidx = (size_t)(i0 + srow) * KLENh + j0 + jc;
            float4 sv = *reinterpret_cast<const float4*>(probb + gidx);
            float p0 = (j0 + jc + 0 <= ilim) ? __expf(sv.x - sm) * srl : 0.f;
            float p1 = (j0 + jc + 1 <= ilim) ? __expf(sv.y - sm) * srl : 0.f;
            float p2 = (j0 + jc + 2 <= ilim) ? __expf(sv.z - sm) * srl : 0.f;
            float p3 = (j0 + jc + 3 <= ilim) ? __expf(sv.w - sm) * srl : 0.f;
            float4 pv = {p0, p1, p2, p3};
            *reinterpret_cast<float4*>(probb + gidx) = pv;
            Ps[srow][jc + 0] = p0; Ps[srow][jc + 1] = p1;
            Ps[srow][jc + 2] = p2; Ps[srow][jc + 3] = p3;
        }
        // V tile
        {
            int jj = tid & 63;
            int dq0 = (tid >> 6) * 4;
#pragma unroll
            for (int kx = 0; kx < 4; ++kx) {
                int dq = dq0 + kx * 16;
                float4 v = *reinterpret_cast<const float4*>(
                    Vb + (size_t)(j0 + jj) * 64 + dq);
                Vs[jj][dq + 0] = v.x; Vs[jj][dq + 1] = v.y;
                Vs[jj][dq + 2] = v.z; Vs[jj][dq + 3] = v.w;
            }
        }
        __syncthreads();
#pragma unroll 8
        for (int jj = 0; jj < 64; ++jj) {
            float v0 = Vs[jj][d0], v1 = Vs[jj][d0 + 1];
#pragma unroll
            for (int u = 0; u < 4; ++u) {
                float p = Ps[rg * 4 + u][jj];
                acc[u][0] += p * v0;
                acc[u][1] += p * v1;
            }
        }
    }
#pragma unroll
    for (int u = 0; u < 4; ++u) {
        size_t o = ((size_t)(i0 + rg * 4 + u) * BSZh + b) * HIDh + n * 64 + d0;
        av[o]     = acc[u][0];
        av[o + 1] = acc[u][1];
    }
}

// ---------------------------------------------------------------------------
extern "C" void kernel_launch(void* const* d_in, const int* in_sizes, int n_in,
                              void* d_out, int out_size, void* d_ws, size_t ws_size,
                              hipStream_t stream)
{
    (void)in_sizes; (void)n_in; (void)out_size; (void)ws_size;
    const float* w    = (const float*)d_in[0];
    const float* r    = (const float*)d_in[1];
    const float* rwb  = (const float*)d_in[2];
    const float* rrb  = (const float*)d_in[3];
    const float* mems = (const float*)d_in[4];
    const float* Wqkv = (const float*)d_in[5];
    const float* Wr   = (const float*)d_in[6];
    const float* Wo   = (const float*)d_in[7];

    float* out  = (float*)d_out;
    float* prob = out + (size_t)QLENh * BSZh * DMh;   // 2,097,152 floats in

    float* ws = (float*)d_ws;
    float* Qw = ws;                    // 2*16*1024*64 = 2,097,152
    float* Qr = Qw + 2097152;
    float* Kt = Qr + 2097152;          // 2*16*2048*64 = 4,194,304
    float* Vt = Kt + 4194304;
    float* RK = Vt + 4194304;          // 16*2048*64   = 2,097,152
    float* AV = RK + 2097152;          // 2048*1024    = 2,097,152
    float* st = AV + 2097152;          // 32768*2

    dim3 blk(256);
    gemm_k<0><<<dim3(24, 32), blk, 0, stream>>>(mems, w, Wqkv, Qw, Qr, Kt, Vt, rwb, rrb);
    gemm_k<1><<<dim3(8, 16), blk, 0, stream>>>(r, nullptr, Wr, RK, nullptr, nullptr, nullptr,
                                               nullptr, nullptr);
    score_k<<<dim3(32, NHh, BSZh), blk, 0, stream>>>(Qw, Qr, Kt, RK, prob, st);
    attnv_k<<<dim3(32, NHh, BSZh), blk, 0, stream>>>(Vt, st, prob, AV);
    gemm_k<2><<<dim3(8, 16), blk, 0, stream>>>(AV, nullptr, Wo, out, nullptr, nullptr, nullptr,
                                               nullptr, nullptr);
}

// Round 3
// 727.375 us; speedup vs baseline: 1.9467x; 1.9467x over previous
//
#include <hip/hip_runtime.h>
#include <math.h>

#define NHh   16
#define QL    1024
#define KL    2048
#define SCALEh 0.125f

typedef __attribute__((ext_vector_type(8))) short s8v;
typedef __attribute__((ext_vector_type(4))) float f4v;

#define MFMA16(a,b,c) __builtin_amdgcn_mfma_f32_16x16x32_bf16((a),(b),(c),0,0,0)

__device__ __forceinline__ short f2bf(float x) {
  unsigned u = __float_as_uint(x);
  return (short)((u + 0x7fffu + ((u >> 16) & 1u)) >> 16);
}
__device__ __forceinline__ float bf2f(short s) {
  return __uint_as_float(((unsigned)(unsigned short)s) << 16);
}

// ---------------------------------------------------------------------------
// split-bf16 MFMA GEMM: C[m][n] = sum_k A[m][k]*Bmat[n][k], K=1024, tile 128x128
// MODE0: A=[mems;w] (M=4096), N=3072; epilogue: Qw/Qr hi/lo (+bias), K hi/lo, V^T bf16
// MODE1: A=r (M=2048), N=1024; epilogue: RK hi/lo [head][row][d]
// MODE2: A=avp0+avp1 (M=2048), N=1024; epilogue: out fp32
// LDS XOR swizzle: slot = row*8 + (kgroup ^ (row&7)); row stride 128B -> 2-way reads
// ---------------------------------------------------------------------------
template<int MODE>
__global__ __launch_bounds__(256)
void gemm_mfma(const float* __restrict__ A0, const float* __restrict__ A1,
               const float* __restrict__ Bmat,
               short* __restrict__ P0h, short* __restrict__ P0l,
               short* __restrict__ P1h, short* __restrict__ P1l,
               short* __restrict__ P2h, short* __restrict__ P2l,
               short* __restrict__ P3,
               float* __restrict__ Ofp,
               const float* __restrict__ rwb, const float* __restrict__ rrb)
{
  __shared__ short Ah[128*64];
  __shared__ short Al[128*64];
  __shared__ short Bh[128*64];
  __shared__ short Bl[128*64];
  const int n0 = blockIdx.x * 128, m0 = blockIdx.y * 128;
  if (MODE == 0 && n0 < 1024 && m0 < 2048) return;   // q rows t<1024 are discarded
  const int tid = threadIdx.x;
  const int L = tid & 63, lr = L & 15, lg = L >> 4;
  const int wid = tid >> 6, wm = wid >> 1, wn = wid & 1;
  const int srow = tid >> 1, sseg = tid & 1;

  const float* arow;
  const float* arow2 = nullptr;
  if (MODE == 0) {
    int m = m0 + srow;
    arow = (m < 2048) ? (A0 + (size_t)m * 1024) : (A1 + (size_t)(m - 2048) * 1024);
  } else {
    arow = A0 + (size_t)(m0 + srow) * 1024;
    if (MODE == 2) arow2 = A1 + (size_t)(m0 + srow) * 1024;
  }
  const float* brow = Bmat + (size_t)(n0 + srow) * 1024;

  const f4v fz = {0.f, 0.f, 0.f, 0.f};
  f4v acc[4][4];
#pragma unroll
  for (int a = 0; a < 4; ++a)
#pragma unroll
    for (int bq = 0; bq < 4; ++bq) acc[a][bq] = fz;

  for (int k0 = 0; k0 < 1024; k0 += 64) {
    __syncthreads();
    {
      const float* pa = arow + k0 + sseg * 32;
#pragma unroll
      for (int v = 0; v < 4; ++v) {
        float4 f0 = *reinterpret_cast<const float4*>(pa + v * 8);
        float4 f1 = *reinterpret_cast<const float4*>(pa + v * 8 + 4);
        if (MODE == 2) {
          const float* pa2 = arow2 + k0 + sseg * 32;
          float4 g0 = *reinterpret_cast<const float4*>(pa2 + v * 8);
          float4 g1 = *reinterpret_cast<const float4*>(pa2 + v * 8 + 4);
          f0.x += g0.x; f0.y += g0.y; f0.z += g0.z; f0.w += g0.w;
          f1.x += g1.x; f1.y += g1.y; f1.z += g1.z; f1.w += g1.w;
        }
        float bf[8] = {f0.x, f0.y, f0.z, f0.w, f1.x, f1.y, f1.z, f1.w};
        s8v hi, lo;
#pragma unroll
        for (int e = 0; e < 8; ++e) {
          short h = f2bf(bf[e]); hi[e] = h; lo[e] = f2bf(bf[e] - bf2f(h));
        }
        int slot = srow * 8 + ((sseg * 4 + v) ^ (srow & 7));
        *reinterpret_cast<s8v*>(Ah + slot * 8) = hi;
        *reinterpret_cast<s8v*>(Al + slot * 8) = lo;
      }
      const float* pb = brow + k0 + sseg * 32;
#pragma unroll
      for (int v = 0; v < 4; ++v) {
        float4 f0 = *reinterpret_cast<const float4*>(pb + v * 8);
        float4 f1 = *reinterpret_cast<const float4*>(pb + v * 8 + 4);
        float bf[8] = {f0.x, f0.y, f0.z, f0.w, f1.x, f1.y, f1.z, f1.w};
        s8v hi, lo;
#pragma unroll
        for (int e = 0; e < 8; ++e) {
          short h = f2bf(bf[e]); hi[e] = h; lo[e] = f2bf(bf[e] - bf2f(h));
        }
        int slot = srow * 8 + ((sseg * 4 + v) ^ (srow & 7));
        *reinterpret_cast<s8v*>(Bh + slot * 8) = hi;
        *reinterpret_cast<s8v*>(Bl + slot * 8) = lo;
      }
    }
    __syncthreads();
#pragma unroll
    for (int ks = 0; ks < 2; ++ks) {
      s8v a_h[4], a_l[4], b_h[4], b_l[4];
#pragma unroll
      for (int x = 0; x < 4; ++x) {
        int ra = wm * 64 + x * 16 + lr;
        int sa = ra * 8 + ((ks * 4 + lg) ^ (ra & 7));
        a_h[x] = *reinterpret_cast<const s8v*>(Ah + sa * 8);
        a_l[x] = *reinterpret_cast<const s8v*>(Al + sa * 8);
        int rb = wn * 64 + x * 16 + lr;
        int sb = rb * 8 + ((ks * 4 + lg) ^ (rb & 7));
        b_h[x] = *reinterpret_cast<const s8v*>(Bh + sb * 8);
        b_l[x] = *reinterpret_cast<const s8v*>(Bl + sb * 8);
      }
#pragma unroll
      for (int mf = 0; mf < 4; ++mf)
#pragma unroll
        for (int nf = 0; nf < 4; ++nf) {
          acc[mf][nf] = MFMA16(a_l[mf], b_h[nf], acc[mf][nf]);
          acc[mf][nf] = MFMA16(a_h[mf], b_l[nf], acc[mf][nf]);
          acc[mf][nf] = MFMA16(a_h[mf], b_h[nf], acc[mf][nf]);
        }
    }
  }
  // ---- epilogue: C/D layout col=lane&15, row=(lane>>4)*4+reg (m89-verified)
  const int sec = (MODE == 0) ? (n0 >> 10) : 0;
#pragma unroll
  for (int mf = 0; mf < 4; ++mf)
#pragma unroll
    for (int nf = 0; nf < 4; ++nf) {
      const int n = n0 + wn * 64 + nf * 16 + lr;
#pragma unroll
      for (int r = 0; r < 4; ++r) {
        const int m = m0 + wm * 64 + mf * 16 + lg * 4 + r;
        float val = acc[mf][nf][r];
        if (MODE == 2) {
          Ofp[(size_t)m * 1024 + n] = val;
        } else if (MODE == 1) {
          int nn = n >> 6, d = n & 63;
          size_t idx = (((size_t)nn * KL + m) << 6) + d;
          short h = f2bf(val);
          P0h[idx] = h; P0l[idx] = f2bf(val - bf2f(h));
        } else {
          int b = m & 1, t = m >> 1;
          if (sec == 0) {                       // q section: t >= 1024 guaranteed
            int i = t - 1024;
            int nn = n >> 6, d = n & 63;
            size_t idx = (((size_t)(b * NHh + nn) * QL + i) << 6) + d;
            float qw = val + rwb[n];
            float qr = val + rrb[n];
            short h = f2bf(qw);
            P0h[idx] = h; P0l[idx] = f2bf(qw - bf2f(h));
            h = f2bf(qr);
            P1h[idx] = h; P1l[idx] = f2bf(qr - bf2f(h));
          } else if (sec == 1) {                // K
            int c = n - 1024; int nn = c >> 6, d = c & 63;
            size_t idx = (((size_t)(b * NHh + nn) * KL + t) << 6) + d;
            short h = f2bf(val);
            P2h[idx] = h; P2l[idx] = f2bf(val - bf2f(h));
          } else {                              // V^T single bf16 [bn][d][t]
            int c = n - 2048; int nn = c >> 6, d = c & 63;
            size_t idx = ((size_t)(b * NHh + nn) * 64 + d) * KL + t;
            P3[idx] = f2bf(val);
          }
        }
      }
    }
}

// ---------------------------------------------------------------------------
// Attention passes. 1 wave / block, 32 q-rows, no barriers, no tile staging.
// PASS0: per-row online (max, sumexp) partials over this block's j-half.
// PASS1: prob = exp(s-m)/l written once; PV accumulated via MFMA into av partial.
// BD rel-shift: G[ir][c] = Qr[i0+ir]*RK[BASE+c], BASE = 992-i0+j0; element gather
// c = 31 - ir + jr (verified: ir=0,jr=0 -> RK[1023-i+j]; ir=31,jr=0 -> RK[base]).
// ---------------------------------------------------------------------------
template<int PASS>
__global__ __launch_bounds__(64)
void attn_pass(const short* __restrict__ Qwh, const short* __restrict__ Qwl,
               const short* __restrict__ Qrh, const short* __restrict__ Qrl,
               const short* __restrict__ Kh,  const short* __restrict__ Klo,
               const short* __restrict__ RKh, const short* __restrict__ RKl,
               const short* __restrict__ Vb,
               const float* __restrict__ statsIn,
               float* __restrict__ statsOut,
               float* __restrict__ prob,
               float* __restrict__ avp)
{
  __shared__ float Gs[96 * 20];     // [c][i16] fp32, pad 20 -> conflict-light
  __shared__ short Ps[32 * 72];     // P tile bf16 for PV A-frags
  const int L = threadIdx.x;
  const int lr = L & 15, lg = L >> 4;
  const int iblk = blockIdx.x >> 1, jh = blockIdx.x & 1;
  const int nh = blockIdx.y, b = blockIdx.z, bn = b * NHh + nh;
  const int i0 = iblk * 32;
  const f4v fz = {0.f, 0.f, 0.f, 0.f};

  // Q A-frags held in registers for the whole kernel (A row = lane&15)
  s8v qw_h[2][2], qw_l[2][2], qr_h[2][2], qr_l[2][2];
#pragma unroll
  for (int mf = 0; mf < 2; ++mf)
#pragma unroll
    for (int ks = 0; ks < 2; ++ks) {
      size_t idx = (((size_t)bn * QL + i0 + mf * 16 + lr) << 6) + ks * 32 + lg * 8;
      qw_h[mf][ks] = *reinterpret_cast<const s8v*>(Qwh + idx);
      qw_l[mf][ks] = *reinterpret_cast<const s8v*>(Qwl + idx);
      qr_h[mf][ks] = *reinterpret_cast<const s8v*>(Qrh + idx);
      qr_l[mf][ks] = *reinterpret_cast<const s8v*>(Qrl + idx);
    }

  float mrun[2][4], lrun[2][4];
  float mfin[2][4], rlf[2][4];
#pragma unroll
  for (int mf = 0; mf < 2; ++mf)
#pragma unroll
    for (int r = 0; r < 4; ++r) { mrun[mf][r] = -INFINITY; lrun[mf][r] = 0.f; }
  if (PASS == 1) {
#pragma unroll
    for (int mf = 0; mf < 2; ++mf)
#pragma unroll
      for (int r = 0; r < 4; ++r) {
        int i = i0 + mf * 16 + lg * 4 + r;
        mfin[mf][r] = statsIn[((size_t)bn * QL + i) * 2];
        rlf[mf][r]  = statsIn[((size_t)bn * QL + i) * 2 + 1];
      }
  }
  f4v av[2][4];
#pragma unroll
  for (int mf = 0; mf < 2; ++mf)
#pragma unroll
    for (int df = 0; df < 4; ++df) av[mf][df] = fz;

  float* probb = prob + (size_t)bn * QL * KL;
  const int jt0 = jh * 16;
  int jtC = ((i0 + 31 + 1024) >> 6) + 1;
  if (jtC > jt0 + 16) jtC = jt0 + 16;

  for (int jt = jt0; jt < jtC; ++jt) {
    const int j0 = jt * 64;
    const int BASE = 992 - i0 + j0;
    // ---- G window GEMM (both mf, shared RK frag loads)
    f4v gacc[2][5];
#pragma unroll
    for (int mf = 0; mf < 2; ++mf)
#pragma unroll
      for (int gi = 0; gi < 5; ++gi) gacc[mf][gi] = fz;
#pragma unroll
    for (int ci = 0; ci < 6; ++ci) {
      int rg = BASE + ci * 16 + lr;
      rg = rg < 0 ? 0 : (rg > 2047 ? 2047 : rg);   // clamped rows feed only masked elems
      size_t ridx = ((size_t)nh * KL + rg) << 6;
      s8v r_h[2], r_l[2];
#pragma unroll
      for (int ks = 0; ks < 2; ++ks) {
        r_h[ks] = *reinterpret_cast<const s8v*>(RKh + ridx + ks * 32 + lg * 8);
        r_l[ks] = *reinterpret_cast<const s8v*>(RKl + ridx + ks * 32 + lg * 8);
      }
#pragma unroll
      for (int mf = 0; mf < 2; ++mf) {
        if (mf == 0 && ci == 0) continue;   // mf0 uses c in [16,95]
        if (mf == 1 && ci == 5) continue;   // mf1 uses c in [0,79]
        const int gi = (mf == 0) ? (ci - 1) : ci;
#pragma unroll
        for (int ks = 0; ks < 2; ++ks) {
          gacc[mf][gi] = MFMA16(qr_l[mf][ks], r_h[ks], gacc[mf][gi]);
          gacc[mf][gi] = MFMA16(qr_h[mf][ks], r_l[ks], gacc[mf][gi]);
          gacc[mf][gi] = MFMA16(qr_h[mf][ks], r_h[ks], gacc[mf][gi]);
        }
      }
    }
    // ---- per mf: spill G, AC GEMM, gather, consume
#pragma unroll
    for (int mf = 0; mf < 2; ++mf) {
#pragma unroll
      for (int gi = 0; gi < 5; ++gi) {
        int c = (mf == 0 ? 16 : 0) + gi * 16 + lr;
        *reinterpret_cast<f4v*>(Gs + c * 20 + lg * 4) = gacc[mf][gi];
      }
      f4v sfr[4];
#pragma unroll
      for (int jf = 0; jf < 4; ++jf) {
        sfr[jf] = fz;
        size_t kidx = ((size_t)bn * KL + j0 + jf * 16 + lr) << 6;
#pragma unroll
        for (int ks = 0; ks < 2; ++ks) {
          s8v k_h = *reinterpret_cast<const s8v*>(Kh  + kidx + ks * 32 + lg * 8);
          s8v k_l = *reinterpret_cast<const s8v*>(Klo + kidx + ks * 32 + lg * 8);
          sfr[jf] = MFMA16(qw_l[mf][ks], k_h, sfr[jf]);
          sfr[jf] = MFMA16(qw_h[mf][ks], k_l, sfr[jf]);
          sfr[jf] = MFMA16(qw_h[mf][ks], k_h, sfr[jf]);
        }
      }
#pragma unroll
      for (int jf = 0; jf < 4; ++jf) {
#pragma unroll
        for (int r = 0; r < 4; ++r) {
          const int irow16 = lg * 4 + r;
          const int i = i0 + mf * 16 + irow16;
          const int j = j0 + jf * 16 + lr;
          const int c = 31 - mf * 16 - irow16 + jf * 16 + lr;
          float g = Gs[c * 20 + irow16];
          float s = (sfr[jf][r] + g) * SCALEh;
          bool valid = (j <= i + 1024);
          if (PASS == 0) {
            if (valid) {
              float mn = fmaxf(mrun[mf][r], s);
              float sc = (lrun[mf][r] > 0.f) ? __expf(mrun[mf][r] - mn) : 0.f;
              lrun[mf][r] = lrun[mf][r] * sc + __expf(s - mn);
              mrun[mf][r] = mn;
            }
          } else {
            float p = valid ? __expf(s - mfin[mf][r]) * rlf[mf][r] : 0.f;
            probb[(size_t)i * KL + j] = p;
            Ps[(mf * 16 + irow16) * 72 + jf * 16 + lr] = f2bf(p);
          }
        }
      }
    }
    if (PASS == 1) {
      // ---- PV: AV[i][d] += P[i][j]*V^T[d][j]
#pragma unroll
      for (int ks = 0; ks < 2; ++ks) {
        s8v pa[2];
#pragma unroll
        for (int mf = 0; mf < 2; ++mf)
          pa[mf] = *reinterpret_cast<const s8v*>(Ps + (mf * 16 + lr) * 72 + ks * 32 + lg * 8);
#pragma unroll
        for (int df = 0; df < 4; ++df) {
          s8v vfr = *reinterpret_cast<const s8v*>(
              Vb + ((size_t)bn * 64 + df * 16 + lr) * KL + j0 + ks * 32 + lg * 8);
#pragma unroll
          for (int mf = 0; mf < 2; ++mf)
            av[mf][df] = MFMA16(pa[mf], vfr, av[mf][df]);
        }
      }
    }
  }

  if (PASS == 0) {
#pragma unroll
    for (int mf = 0; mf < 2; ++mf)
#pragma unroll
      for (int r = 0; r < 4; ++r) {
        float m = mrun[mf][r], l = lrun[mf][r];
#pragma unroll
        for (int mk = 1; mk <= 8; mk <<= 1) {
          float mo = __shfl_xor(m, mk, 64);
          float lo = __shfl_xor(l, mk, 64);
          float mn = fmaxf(m, mo);
          float t1 = (l  > 0.f) ? l  * __expf(m  - mn) : 0.f;
          float t2 = (lo > 0.f) ? lo * __expf(mo - mn) : 0.f;
          m = mn; l = t1 + t2;
        }
        if (lr == 0) {
          int i = i0 + mf * 16 + lg * 4 + r;
          size_t o = ((size_t)jh * 32768 + (size_t)bn * QL + i) * 2;
          statsOut[o] = m; statsOut[o + 1] = l;
        }
      }
  } else {
    // zero fully-masked tiles of this j-half
    for (int jt = jtC; jt < jt0 + 16; ++jt) {
      const int j0 = jt * 64;
      float4 z = {0.f, 0.f, 0.f, 0.f};
      int row = L >> 1, cb = (L & 1) * 32;
#pragma unroll
      for (int q = 0; q < 8; ++q)
        *reinterpret_cast<float4*>(probb + (size_t)(i0 + row) * KL + j0 + cb + q * 4) = z;
    }
    // write av partial [jh][(i*2+b)][1024]
#pragma unroll
    for (int mf = 0; mf < 2; ++mf)
#pragma unroll
      for (int df = 0; df < 4; ++df)
#pragma unroll
        for (int r = 0; r < 4; ++r) {
          int i = i0 + mf * 16 + lg * 4 + r;
          int d = df * 16 + lr;
          avp[(size_t)jh * 2097152 + ((size_t)i * 2 + b) * 1024 + nh * 64 + d] = av[mf][df][r];
        }
  }
}

__global__ __launch_bounds__(256)
void stats_combine(const float* __restrict__ sp, float* __restrict__ st)
{
  int idx = blockIdx.x * 256 + threadIdx.x;   // 32768 rows
  float m0 = sp[(size_t)idx * 2],         l0 = sp[(size_t)idx * 2 + 1];
  float m1 = sp[65536 + (size_t)idx * 2], l1 = sp[65536 + (size_t)idx * 2 + 1];
  float m = fmaxf(m0, m1);
  float l = ((l0 > 0.f) ? l0 * __expf(m0 - m) : 0.f)
          + ((l1 > 0.f) ? l1 * __expf(m1 - m) : 0.f);
  st[(size_t)idx * 2] = m;
  st[(size_t)idx * 2 + 1] = 1.0f / l;
}

// ---------------------------------------------------------------------------
extern "C" void kernel_launch(void* const* d_in, const int* in_sizes, int n_in,
                              void* d_out, int out_size, void* d_ws, size_t ws_size,
                              hipStream_t stream)
{
  (void)in_sizes; (void)n_in; (void)out_size; (void)ws_size;
  const float* w    = (const float*)d_in[0];
  const float* r    = (const float*)d_in[1];
  const float* rwb  = (const float*)d_in[2];
  const float* rrb  = (const float*)d_in[3];
  const float* mems = (const float*)d_in[4];
  const float* Wqkv = (const float*)d_in[5];
  const float* Wr   = (const float*)d_in[6];
  const float* Wo   = (const float*)d_in[7];

  float* out  = (float*)d_out;
  float* prob = out + 2097152;

  // workspace (67,371,008 B total, same footprint as the passing round-1 kernel)
  short* Qwh = (short*)d_ws;
  short* Qwl = Qwh + 2097152;
  short* Qrh = Qwl + 2097152;
  short* Qrl = Qrh + 2097152;
  short* Kh  = Qrl + 2097152;
  short* Klo = Kh  + 4194304;
  short* Vb  = Klo + 4194304;
  short* RKh = Vb  + 4194304;
  short* RKl = RKh + 2097152;
  float* avp    = (float*)(RKl + 2097152);  // 2 x 2,097,152 floats
  float* statsP = avp;                      // aliased: consumed before avp written
  float* stats  = avp + 4194304;            // 32768 x 2 floats

  gemm_mfma<0><<<dim3(24, 32), 256, 0, stream>>>(
      mems, w, Wqkv, Qwh, Qwl, Qrh, Qrl, Kh, Klo, Vb, nullptr, rwb, rrb);
  gemm_mfma<1><<<dim3(8, 16), 256, 0, stream>>>(
      r, nullptr, Wr, RKh, RKl, nullptr, nullptr, nullptr, nullptr, nullptr,
      nullptr, nullptr, nullptr);
  attn_pass<0><<<dim3(64, NHh, 2), 64, 0, stream>>>(
      Qwh, Qwl, Qrh, Qrl, Kh, Klo, RKh, RKl, Vb, stats, statsP, prob, avp);
  stats_combine<<<128, 256, 0, stream>>>(statsP, stats);
  attn_pass<1><<<dim3(64, NHh, 2), 64, 0, stream>>>(
      Qwh, Qwl, Qrh, Qrl, Kh, Klo, RKh, RKl, Vb, stats, statsP, prob, avp);
  gemm_mfma<2><<<dim3(8, 16), 256, 0, stream>>>(
      avp, avp + 2097152, Wo, nullptr, nullptr, nullptr, nullptr, nullptr, nullptr,
      nullptr, out, nullptr, nullptr);
}